// Round 2
// baseline (422.514 us; speedup 1.0000x reference)
//
#include <hip/hip_runtime.h>
#include <math.h>

// Problem constants
#define B_DIM 8
#define T_DIM 2048
#define C_DIM 1024
#define HS_DIM 128
#define VD 256
#define M_DIM (B_DIM * T_DIM)            // 16384 rows
#define QK_ELEMS (M_DIM * HS_DIM)        // 2,097,152 elems per (q|k) term
#define SCALE 0.088388347648318447f      // 1/sqrt(128)
#define LOG_THETA 9.210340371976184f     // ln(10000)

// workspace layout (ushort units)
#define QB_OFF   0u
#define KB_OFF   4194304u
#define VT_OFF   8388608u
#define WT_OFF   12582912u
#define XBH_OFF  13369344u               // x-bf16 rows 8192..16383
#define LAM_OFF  21757952u
#define XSPLIT_ELEMS 8388608u            // rows 0..8191 of x-bf16 live in d_out

typedef short s8v   __attribute__((ext_vector_type(8)));   // 8 bf16 (4 VGPRs)
typedef float f32x4 __attribute__((ext_vector_type(4)));
typedef float f32x16 __attribute__((ext_vector_type(16)));

// ---------- helpers ----------
__device__ __forceinline__ unsigned int bf16_rne(float f) {
    unsigned int u = __float_as_uint(f);
    return (u + 0x7fffu + ((u >> 16) & 1u)) >> 16;
}
__device__ __forceinline__ unsigned int pack_bf2(float lo, float hi) {
    return bf16_rne(lo) | (bf16_rne(hi) << 16);
}
__device__ __forceinline__ void async_cp16(const unsigned short* g, unsigned short* l) {
    __builtin_amdgcn_global_load_lds(
        (const __attribute__((address_space(1))) unsigned int*)g,
        (__attribute__((address_space(3))) unsigned int*)l, 16, 0, 0);
}

// ---------- kernel 1: lambda coefficients ----------
__global__ void lam_kernel(const float* __restrict__ lq, const float* __restrict__ lk,
                           const int* __restrict__ lidx, float* __restrict__ lam_out) {
    int t = threadIdx.x; // 64 threads = 1 wave
    float s0 = expf(lq[t] * lk[t]) + expf(lq[t + 64] * lk[t + 64]);
    float s1 = expf(lq[128 + t] * lk[128 + t]) + expf(lq[192 + t] * lk[192 + t]);
    #pragma unroll
    for (int off = 32; off > 0; off >>= 1) {
        s0 += __shfl_down(s0, off);
        s1 += __shfl_down(s1, off);
    }
    if (t == 0) {
        float e0 = s0 * (1.0f / 128.0f);
        float e1 = s1 * (1.0f / 128.0f);
        float li = 0.8f - 0.6f * expf(-0.3f * ((float)lidx[0] - 1.0f));
        lam_out[0] = e0 + li;            // +lam0
        lam_out[1] = -(e1 - e0 + li);    // -lam1
    }
}

// ---------- kernel 2a: cast x -> bf16 (split across d_out scratch + ws) ----------
__global__ __launch_bounds__(256) void cast_x_kernel(const float* __restrict__ x,
                                                     unsigned short* __restrict__ lo,
                                                     unsigned short* __restrict__ hi) {
    const size_t i8 = ((size_t)blockIdx.x * 256 + threadIdx.x) * 8;
    float4 a = *(const float4*)(x + i8);
    float4 b = *(const float4*)(x + i8 + 4);
    uint4 u;
    u.x = pack_bf2(a.x, a.y); u.y = pack_bf2(a.z, a.w);
    u.z = pack_bf2(b.x, b.y); u.w = pack_bf2(b.z, b.w);
    unsigned short* dst = (i8 < XSPLIT_ELEMS) ? (lo + i8) : (hi + (i8 - XSPLIT_ELEMS));
    *(uint4*)dst = u;
}

// ---------- kernel 2b: build Wt[768][1024] bf16 (transposed, concatenated) ----
__global__ __launch_bounds__(256) void cast_wt_kernel(
    const float* __restrict__ Wq, const float* __restrict__ Wk,
    const float* __restrict__ Wv, unsigned short* __restrict__ wt) {
    __shared__ float tile[32][33];
    const int t = threadIdx.x;
    const int n0 = blockIdx.x * 32;
    const int k0 = blockIdx.y * 32;
    const int seg = n0 >> 7;
    const int nl = t & 31;
    const int ng = n0 + nl;
    const float* src; int ld;
    if (seg < 2)      { src = Wq + (size_t)seg * (C_DIM * HS_DIM) + (ng & 127); ld = 128; }
    else if (seg < 4) { src = Wk + (size_t)(seg - 2) * (C_DIM * HS_DIM) + (ng & 127); ld = 128; }
    else              { src = Wv + (ng - 512); ld = 256; }
    #pragma unroll
    for (int rep = 0; rep < 4; ++rep) {
        int kl = (t >> 5) + rep * 8;
        tile[kl][nl] = src[(size_t)(k0 + kl) * ld];
    }
    __syncthreads();
    unsigned int* wt32 = (unsigned int*)wt;
    #pragma unroll
    for (int rep = 0; rep < 2; ++rep) {
        int nl2 = (t >> 4) + rep * 16;
        int k2 = (t & 15) * 2;
        unsigned int u = pack_bf2(tile[k2][nl2], tile[k2 + 1][nl2]);
        wt32[((size_t)(n0 + nl2) * 1024 + k0 + k2) >> 1] = u;
    }
}

// ---------- kernel 2c: bf16 MFMA GEMM + RoPE / V-transpose epilogue ----------
__global__ __launch_bounds__(256) void gemm_kernel(
    const unsigned short* __restrict__ xlo, const unsigned short* __restrict__ xhi,
    const unsigned short* __restrict__ wt,
    unsigned short* __restrict__ qo, unsigned short* __restrict__ ko,
    unsigned short* __restrict__ vo) {
    __shared__ unsigned short As[128 * 32];   // 8 KB, row-major [128][32]
    __shared__ unsigned short Bs[128 * 32];   // 8 KB, row-major [128][32]

    const int t = threadIdx.x;
    const int wv = t >> 6, lane = t & 63;
    const int quad = lane >> 4, l15 = lane & 15;
    const int m0 = blockIdx.x * 128;
    const int n0 = blockIdx.y * 128;
    const int wr = wv >> 1, wc = wv & 1;

    const unsigned short* xbase = (m0 < 8192)
        ? (xlo + (size_t)m0 * C_DIM) : (xhi + (size_t)(m0 - 8192) * C_DIM);

    f32x4 acc[4][4];
    #pragma unroll
    for (int i = 0; i < 4; ++i)
        #pragma unroll
        for (int j = 0; j < 4; ++j) acc[i][j] = (f32x4){0.f, 0.f, 0.f, 0.f};

    const int srow = lane >> 2;
    const int skof = (lane & 3) * 8;

    for (int k0 = 0; k0 < C_DIM; k0 += 32) {
        #pragma unroll
        for (int j = 0; j < 2; ++j) {
            const int c = wv * 2 + j;
            async_cp16(xbase + (size_t)(c * 16 + srow) * C_DIM + k0 + skof, As + c * 512);
        }
        #pragma unroll
        for (int j = 0; j < 2; ++j) {
            const int c = wv * 2 + j;
            async_cp16(wt + (size_t)(n0 + c * 16 + srow) * C_DIM + k0 + skof, Bs + c * 512);
        }
        __syncthreads();
        s8v af[4], bf[4];
        #pragma unroll
        for (int i = 0; i < 4; ++i)
            af[i] = *(const s8v*)&As[(wr * 64 + i * 16 + l15) * 32 + quad * 8];
        #pragma unroll
        for (int j = 0; j < 4; ++j)
            bf[j] = *(const s8v*)&Bs[(wc * 64 + j * 16 + l15) * 32 + quad * 8];
        #pragma unroll
        for (int i = 0; i < 4; ++i)
            #pragma unroll
            for (int j = 0; j < 4; ++j)
                acc[i][j] = __builtin_amdgcn_mfma_f32_16x16x32_bf16(af[i], bf[j], acc[i][j], 0, 0, 0);
        __syncthreads();
    }

    const int seg = n0 >> 7;   // 0..5
    if (seg < 4) {
        unsigned short* dstbuf = ((seg < 2) ? qo : ko) + (size_t)(seg & 1) * QK_ELEMS;
        float freqj[4];
        #pragma unroll
        for (int j = 0; j < 4; ++j) {
            const int d = wc * 64 + j * 16 + l15;
            freqj[j] = __expf((float)(d >> 1) * (-LOG_THETA / 64.f));
        }
        const int odd = lane & 1;
        #pragma unroll
        for (int i = 0; i < 4; ++i) {
            #pragma unroll
            for (int e = 0; e < 4; ++e) {
                const int m = m0 + wr * 64 + i * 16 + quad * 4 + e;
                const float trow = (float)(m & (T_DIM - 1));
                unsigned int* p32 = (unsigned int*)(dstbuf + (size_t)m * HS_DIM);
                #pragma unroll
                for (int j = 0; j < 4; ++j) {
                    const int d = wc * 64 + j * 16 + l15;
                    const float val = acc[i][j][e];
                    const float other = __shfl_xor(val, 1);
                    float sn_, cs_;
                    __sincosf(trow * freqj[j], &sn_, &cs_);
                    const float out = val * cs_ + (odd ? other * sn_ : -other * sn_);
                    const float out2 = __shfl_xor(out, 1);
                    if (!odd) p32[d >> 1] = pack_bf2(out, out2);
                }
            }
        }
    } else {
        const int bq = m0 >> 11;
        const int tbase = m0 & (T_DIM - 1);
        unsigned int* vT32 = (unsigned int*)vo;
        #pragma unroll
        for (int j = 0; j < 4; ++j) {
            const int d = (seg - 4) * 128 + wc * 64 + j * 16 + l15;
            const size_t rowbase = (size_t)(bq * VD + d) * (T_DIM / 2); // u32 units
            #pragma unroll
            for (int i = 0; i < 4; ++i) {
                const int tok = tbase + wr * 64 + i * 16 + quad * 4;
                uint2 u;
                u.x = pack_bf2(acc[i][j][0], acc[i][j][1]);
                u.y = pack_bf2(acc[i][j][2], acc[i][j][3]);
                *(uint2*)&vT32[rowbase + (tok >> 1)] = u;
            }
        }
    }
}

// ---------- kernel 3: dual-term causal attention, 32x32 bf16 MFMA ----------
// Grid: 512 blocks = 64 strips x 8 batches; strip order pairs complementary
// heavy/light strips under linear CU assignment (id and id+256 sum to 63).
// Block: 256 threads / 4 waves; strip = 32 queries; K-tile = 64 keys.
//
// Round-2: T14 async-STAGE split on the round-0 structure. Round-1's direct
// global->reg fragment loads were a 3x L2-transaction amplification (32
// scattered lines/instr vs 16 coalesced) and regressed 76->141 us. Here the
// staging stays coalesced (uint4, padded LDS) but is software-pipelined:
//   - tile t+1's 16 uint4 loads are ISSUED at the top of tile t (latency
//     hides under QK + exp + PV, ~1000+ cycles of cover),
//   - the ds_writes land after the post-PV barrier, when Ks/Vt are provably
//     consumed, followed by the visibility barrier.
// Same 3 barriers and LDS layout as round 0 (80896 B, 2 blocks/CU); the
// exposed global-load latency per tile (~500-800 cyc) is removed.
// s_setprio(1) wraps the MFMA clusters (T5, +4-7% measured on attn).
#define KSTR 136    // K LDS row stride (bf16)
#define VSTR 72     // Vt LDS row stride: 64 tok + 8 pad
#define PSTR 72     // P LDS row stride: 64 keys + 8 pad
#define OSTR 260    // O combine stride (fp32 words)
#define K_OFF 0
#define V_OFF 34816
#define P_OFF 71680
#define SM_TOTAL 80896

__global__ __launch_bounds__(256, 2) void attn_kernel(
    const unsigned short* __restrict__ qg, const unsigned short* __restrict__ kg,
    const unsigned short* __restrict__ vg, const float* __restrict__ lam,
    float* __restrict__ outp) {
    __shared__ __align__(16) unsigned char smem[SM_TOTAL];
    unsigned short* Ks = (unsigned short*)(smem + K_OFF);  // [2][64][136]
    unsigned short* Vt = (unsigned short*)(smem + V_OFF);  // [256][72]
    unsigned short* Ps = (unsigned short*)(smem + P_OFF);  // [2][32][72]
    float* Ol = (float*)smem;                              // [32][260] overlays K
    float* Lsum = (float*)(smem + P_OFF);                  // [2][2][32] overlays dead Ps

    const int t = threadIdx.x;
    const int id = blockIdx.x;
    const int b = id & 7;                  // batch -> XCD round-robin
    const int sidx = id >> 3;              // 0..63
    const int strip = (sidx < 32) ? (63 - sidx) : (sidx - 32); // complementary pairing
    const int q0 = strip * 32;
    const int nt = (strip >> 1) + 1;       // 64-key tiles

    const int w = t >> 6, lane = t & 63;
    const int l31 = lane & 31, lh = lane >> 5;
    const int term = w & 1;
    const int kh = w >> 1;                 // QK k-half / PV d-half

    const float cn = lam[term];            // lam[1] carries the minus sign

    // Q A-frags (32x32x16 layout: row=lane&31, k=lh*8+j), 8 k-steps in registers
    const unsigned short* qrow = qg
        + ((size_t)(term * B_DIM + b) * T_DIM + q0 + l31) * HS_DIM + lh * 8;
    s8v qa[8];
    #pragma unroll
    for (int ks = 0; ks < 8; ++ks)
        qa[ks] = *(const s8v*)(qrow + ks * 16);

    // ---- per-thread staging geometry (coalesced uint4, round-0 mapping) ----
    // K: idx = t + rep*256 over 2048 uint4s: n=idx>>10, r=(idx&1023)>>4, seg=idx&15
    // V: idx = t + rep*256 over 2048 uint4s: d=idx>>3, seg=idx&7
    const unsigned short* ksrc[8]; int kdst[8];
    const unsigned short* vsrc[8]; int vdst[8];
    #pragma unroll
    for (int rep = 0; rep < 8; ++rep) {
        const int idx = t + rep * 256;
        const int n = idx >> 10, rem = idx & 1023;
        const int r = rem >> 4, seg = rem & 15;
        ksrc[rep] = kg + ((size_t)(n * B_DIM + b) * T_DIM + r) * HS_DIM + seg * 8;
        kdst[rep] = (n * 64 + r) * KSTR + seg * 8;
        const int d = idx >> 3, vseg = idx & 7;
        vsrc[rep] = vg + ((size_t)(b * VD + d) * T_DIM) + vseg * 8;
        vdst[rep] = d * VSTR + vseg * 8;
    }

    f32x16 o[4];
    #pragma unroll
    for (int dt = 0; dt < 4; ++dt)
        #pragma unroll
        for (int r = 0; r < 16; ++r) o[dt][r] = 0.f;
    float l_acc[16];
    #pragma unroll
    for (int r = 0; r < 16; ++r) l_acc[r] = 0.f;

    // ---- prologue: stage tile 0 ----
    uint4 gk[8], gv[8];
    #pragma unroll
    for (int rep = 0; rep < 8; ++rep) {
        gk[rep] = *(const uint4*)(ksrc[rep]);
        gv[rep] = *(const uint4*)(vsrc[rep]);
    }
    #pragma unroll
    for (int rep = 0; rep < 8; ++rep) {
        *(uint4*)&Ks[kdst[rep]] = gk[rep];
        *(uint4*)&Vt[vdst[rep]] = gv[rep];
    }
    __syncthreads();

    for (int it = 0; it < nt; ++it) {
        const int s0 = it * 64;
        const bool has_next = (it + 1) < nt;

        // ---- T14: ISSUE next tile's coalesced loads now; latency hides
        //      under QK + exp + PV; written to LDS after the post-PV barrier.
        if (has_next) {
            const int sn = s0 + 64;
            #pragma unroll
            for (int rep = 0; rep < 8; ++rep) {
                gk[rep] = *(const uint4*)(ksrc[rep] + (size_t)sn * HS_DIM);
                gv[rep] = *(const uint4*)(vsrc[rep] + sn);
            }
        }

        // ---- QK: S[32q x 32k] for (term, khalf) ----
        f32x16 sc;
        #pragma unroll
        for (int r = 0; r < 16; ++r) sc[r] = 0.f;
        __builtin_amdgcn_s_setprio(1);
        #pragma unroll
        for (int ks = 0; ks < 8; ++ks) {
            s8v kf = *(const s8v*)&Ks[(term * 64 + kh * 32 + l31) * KSTR
                                      + ks * 16 + lh * 8];
            sc = __builtin_amdgcn_mfma_f32_32x32x16_bf16(qa[ks], kf, sc, 0, 0, 0);
        }
        __builtin_amdgcn_s_setprio(0);
        // exp + P write (C/D 32x32: col=l31, row=(r&3)+8*(r>>2)+4*lh)
        const int key = s0 + kh * 32 + l31;
        #pragma unroll
        for (int r = 0; r < 16; ++r) {
            const int row = (r & 3) + 8 * (r >> 2) + 4 * lh;
            const float p = (key <= q0 + row) ? __expf(sc[r] * SCALE) : 0.f;
            l_acc[r] += p;
            Ps[(term * 32 + row) * PSTR + kh * 32 + l31] = (unsigned short)bf16_rne(p);
        }
        __syncthreads();

        // ---- PV: O[32q x 128d] += P[32x64] @ V[64x128] for (term, dhalf) ----
        __builtin_amdgcn_s_setprio(1);
        #pragma unroll
        for (int ks = 0; ks < 4; ++ks) {
            s8v pa = *(const s8v*)&Ps[(term * 32 + l31) * PSTR + ks * 16 + lh * 8];
            #pragma unroll
            for (int dt = 0; dt < 4; ++dt) {
                s8v vb = *(const s8v*)&Vt[(kh * 128 + dt * 32 + l31) * VSTR
                                          + ks * 16 + lh * 8];
                o[dt] = __builtin_amdgcn_mfma_f32_32x32x16_bf16(pa, vb, o[dt], 0, 0, 0);
            }
        }
        __builtin_amdgcn_s_setprio(0);
        __syncthreads();   // all Ks/Vt/Ps reads for tile it complete

        // ---- write the prefetched tile into LDS (loads have drained by now) ----
        if (has_next) {
            #pragma unroll
            for (int rep = 0; rep < 8; ++rep) {
                *(uint4*)&Ks[kdst[rep]] = gk[rep];
                *(uint4*)&Vt[vdst[rep]] = gv[rep];
            }
        }
        __syncthreads();   // staged tile visible; P safe to overwrite next iter
    }

    // ---- finalize l: intra-wave reduce over 32 key-columns, then combine
    //      the two kh-wave partials per (term,row) through LDS ----
    #pragma unroll
    for (int r = 0; r < 16; ++r) {
        float lt = l_acc[r];
        #pragma unroll
        for (int off = 1; off < 32; off <<= 1) lt += __shfl_xor(lt, off);
        if (l31 == 0) {
            const int row = (r & 3) + 8 * (r >> 2) + 4 * lh;
            Lsum[(term * 2 + kh) * 32 + row] = lt;
        }
    }
    __syncthreads();
    float inv[16];
    #pragma unroll
    for (int r = 0; r < 16; ++r) {
        const int row = (r & 3) + 8 * (r >> 2) + 4 * lh;
        inv[r] = cn / (Lsum[(term * 2 + 0) * 32 + row] + Lsum[(term * 2 + 1) * 32 + row]);
    }

    // ---- combine terms via LDS overlay on K region ----
    if (term) {
        #pragma unroll
        for (int dt = 0; dt < 4; ++dt)
            #pragma unroll
            for (int r = 0; r < 16; ++r) {
                const int row = (r & 3) + 8 * (r >> 2) + 4 * lh;
                Ol[row * OSTR + kh * 128 + dt * 32 + l31] = o[dt][r] * inv[r];
            }
    }
    __syncthreads();
    if (!term) {
        #pragma unroll
        for (int dt = 0; dt < 4; ++dt)
            #pragma unroll
            for (int r = 0; r < 16; ++r) {
                const int row = (r & 3) + 8 * (r >> 2) + 4 * lh;
                Ol[row * OSTR + kh * 128 + dt * 32 + l31] += o[dt][r] * inv[r];
            }
    }
    __syncthreads();
    #pragma unroll
    for (int rep = 0; rep < 8; ++rep) {
        int idx = t + rep * 256;           // 32 rows x 64 float4
        int row = idx >> 6, c4 = idx & 63;
        float4 val = *(const float4*)&Ol[row * OSTR + c4 * 4];
        *(float4*)&outp[((size_t)(b * T_DIM + q0 + row)) * VD + c4 * 4] = val;
    }
}

extern "C" void kernel_launch(void* const* d_in, const int* in_sizes, int n_in,
                              void* d_out, int out_size, void* d_ws, size_t ws_size,
                              hipStream_t stream) {
    const float* x  = (const float*)d_in[0];
    const float* Wq = (const float*)d_in[1];
    const float* Wk = (const float*)d_in[2];
    const float* Wv = (const float*)d_in[3];
    const float* lq = (const float*)d_in[4];
    const float* lk = (const float*)d_in[5];
    const int* lidx = (const int*)d_in[6];

    unsigned short* ws = (unsigned short*)d_ws;
    unsigned short* qb   = ws + QB_OFF;    // [2][8][2048][128] bf16
    unsigned short* kb   = ws + KB_OFF;    // [2][8][2048][128] bf16
    unsigned short* vTb  = ws + VT_OFF;    // [8][256][2048] bf16
    unsigned short* wtb  = ws + WT_OFF;    // [768][1024] bf16
    unsigned short* xbhi = ws + XBH_OFF;   // x-bf16 rows 8192..16383
    float* lamb = (float*)(ws + LAM_OFF);
    unsigned short* xblo = (unsigned short*)d_out;  // scratch; attn overwrites d_out
    (void)ws_size; (void)in_sizes; (void)n_in; (void)out_size;

    lam_kernel<<<dim3(1), dim3(64), 0, stream>>>(lq, lk, lidx, lamb);
    cast_x_kernel<<<dim3(8192), dim3(256), 0, stream>>>(x, xblo, xbhi);
    cast_wt_kernel<<<dim3(24, 32), dim3(256), 0, stream>>>(Wq, Wk, Wv, wtb);
    gemm_kernel<<<dim3(128, 6), dim3(256), 0, stream>>>(xblo, xbhi, wtb, qb, kb, vTb);
    attn_kernel<<<dim3(512), dim3(256), 0, stream>>>(qb, kb, vTb, lamb, (float*)d_out);
}

// Round 3
// 255.300 us; speedup vs baseline: 1.6550x; 1.6550x over previous
//
#include <hip/hip_runtime.h>
#include <math.h>

// Problem constants
#define B_DIM 8
#define T_DIM 2048
#define C_DIM 1024
#define HS_DIM 128
#define VD 256
#define M_DIM (B_DIM * T_DIM)            // 16384 rows
#define QK_ELEMS (M_DIM * HS_DIM)        // 2,097,152 elems per (q|k) term
#define SCALE 0.088388347648318447f      // 1/sqrt(128)
#define LOG_THETA 9.210340371976184f     // ln(10000)

// workspace layout (ushort units)
#define QB_OFF   0u
#define KB_OFF   4194304u
#define VT_OFF   8388608u
#define WT_OFF   12582912u
#define XBH_OFF  13369344u               // x-bf16 rows 8192..16383
#define LAM_OFF  21757952u
#define XSPLIT_ELEMS 8388608u            // rows 0..8191 of x-bf16 live in d_out

typedef short s8v   __attribute__((ext_vector_type(8)));   // 8 bf16 (4 VGPRs)
typedef float f32x4 __attribute__((ext_vector_type(4)));
typedef float f32x16 __attribute__((ext_vector_type(16)));

// ---------- helpers ----------
__device__ __forceinline__ unsigned int bf16_rne(float f) {
    unsigned int u = __float_as_uint(f);
    return (u + 0x7fffu + ((u >> 16) & 1u)) >> 16;
}
__device__ __forceinline__ unsigned int pack_bf2(float lo, float hi) {
    return bf16_rne(lo) | (bf16_rne(hi) << 16);
}
__device__ __forceinline__ void async_cp16(const unsigned short* g, unsigned short* l) {
    __builtin_amdgcn_global_load_lds(
        (const __attribute__((address_space(1))) unsigned int*)g,
        (__attribute__((address_space(3))) unsigned int*)l, 16, 0, 0);
}

// ---------- kernel 1: lambda coefficients ----------
__global__ void lam_kernel(const float* __restrict__ lq, const float* __restrict__ lk,
                           const int* __restrict__ lidx, float* __restrict__ lam_out) {
    int t = threadIdx.x; // 64 threads = 1 wave
    float s0 = expf(lq[t] * lk[t]) + expf(lq[t + 64] * lk[t + 64]);
    float s1 = expf(lq[128 + t] * lk[128 + t]) + expf(lq[192 + t] * lk[192 + t]);
    #pragma unroll
    for (int off = 32; off > 0; off >>= 1) {
        s0 += __shfl_down(s0, off);
        s1 += __shfl_down(s1, off);
    }
    if (t == 0) {
        float e0 = s0 * (1.0f / 128.0f);
        float e1 = s1 * (1.0f / 128.0f);
        float li = 0.8f - 0.6f * expf(-0.3f * ((float)lidx[0] - 1.0f));
        lam_out[0] = e0 + li;            // +lam0
        lam_out[1] = -(e1 - e0 + li);    // -lam1
    }
}

// ---------- kernel 2a: cast x -> bf16 (split across d_out scratch + ws) ----------
__global__ __launch_bounds__(256) void cast_x_kernel(const float* __restrict__ x,
                                                     unsigned short* __restrict__ lo,
                                                     unsigned short* __restrict__ hi) {
    const size_t i8 = ((size_t)blockIdx.x * 256 + threadIdx.x) * 8;
    float4 a = *(const float4*)(x + i8);
    float4 b = *(const float4*)(x + i8 + 4);
    uint4 u;
    u.x = pack_bf2(a.x, a.y); u.y = pack_bf2(a.z, a.w);
    u.z = pack_bf2(b.x, b.y); u.w = pack_bf2(b.z, b.w);
    unsigned short* dst = (i8 < XSPLIT_ELEMS) ? (lo + i8) : (hi + (i8 - XSPLIT_ELEMS));
    *(uint4*)dst = u;
}

// ---------- kernel 2b: build Wt[768][1024] bf16 (transposed, concatenated) ----
__global__ __launch_bounds__(256) void cast_wt_kernel(
    const float* __restrict__ Wq, const float* __restrict__ Wk,
    const float* __restrict__ Wv, unsigned short* __restrict__ wt) {
    __shared__ float tile[32][33];
    const int t = threadIdx.x;
    const int n0 = blockIdx.x * 32;
    const int k0 = blockIdx.y * 32;
    const int seg = n0 >> 7;
    const int nl = t & 31;
    const int ng = n0 + nl;
    const float* src; int ld;
    if (seg < 2)      { src = Wq + (size_t)seg * (C_DIM * HS_DIM) + (ng & 127); ld = 128; }
    else if (seg < 4) { src = Wk + (size_t)(seg - 2) * (C_DIM * HS_DIM) + (ng & 127); ld = 128; }
    else              { src = Wv + (ng - 512); ld = 256; }
    #pragma unroll
    for (int rep = 0; rep < 4; ++rep) {
        int kl = (t >> 5) + rep * 8;
        tile[kl][nl] = src[(size_t)(k0 + kl) * ld];
    }
    __syncthreads();
    unsigned int* wt32 = (unsigned int*)wt;
    #pragma unroll
    for (int rep = 0; rep < 2; ++rep) {
        int nl2 = (t >> 4) + rep * 16;
        int k2 = (t & 15) * 2;
        unsigned int u = pack_bf2(tile[k2][nl2], tile[k2 + 1][nl2]);
        wt32[((size_t)(n0 + nl2) * 1024 + k0 + k2) >> 1] = u;
    }
}

// ---------- kernel 2c: bf16 MFMA GEMM + RoPE / V-transpose epilogue ----------
__global__ __launch_bounds__(256) void gemm_kernel(
    const unsigned short* __restrict__ xlo, const unsigned short* __restrict__ xhi,
    const unsigned short* __restrict__ wt,
    unsigned short* __restrict__ qo, unsigned short* __restrict__ ko,
    unsigned short* __restrict__ vo) {
    __shared__ unsigned short As[128 * 32];   // 8 KB, row-major [128][32]
    __shared__ unsigned short Bs[128 * 32];   // 8 KB, row-major [128][32]

    const int t = threadIdx.x;
    const int wv = t >> 6, lane = t & 63;
    const int quad = lane >> 4, l15 = lane & 15;
    const int m0 = blockIdx.x * 128;
    const int n0 = blockIdx.y * 128;
    const int wr = wv >> 1, wc = wv & 1;

    const unsigned short* xbase = (m0 < 8192)
        ? (xlo + (size_t)m0 * C_DIM) : (xhi + (size_t)(m0 - 8192) * C_DIM);

    f32x4 acc[4][4];
    #pragma unroll
    for (int i = 0; i < 4; ++i)
        #pragma unroll
        for (int j = 0; j < 4; ++j) acc[i][j] = (f32x4){0.f, 0.f, 0.f, 0.f};

    const int srow = lane >> 2;
    const int skof = (lane & 3) * 8;

    for (int k0 = 0; k0 < C_DIM; k0 += 32) {
        #pragma unroll
        for (int j = 0; j < 2; ++j) {
            const int c = wv * 2 + j;
            async_cp16(xbase + (size_t)(c * 16 + srow) * C_DIM + k0 + skof, As + c * 512);
        }
        #pragma unroll
        for (int j = 0; j < 2; ++j) {
            const int c = wv * 2 + j;
            async_cp16(wt + (size_t)(n0 + c * 16 + srow) * C_DIM + k0 + skof, Bs + c * 512);
        }
        __syncthreads();
        s8v af[4], bf[4];
        #pragma unroll
        for (int i = 0; i < 4; ++i)
            af[i] = *(const s8v*)&As[(wr * 64 + i * 16 + l15) * 32 + quad * 8];
        #pragma unroll
        for (int j = 0; j < 4; ++j)
            bf[j] = *(const s8v*)&Bs[(wc * 64 + j * 16 + l15) * 32 + quad * 8];
        #pragma unroll
        for (int i = 0; i < 4; ++i)
            #pragma unroll
            for (int j = 0; j < 4; ++j)
                acc[i][j] = __builtin_amdgcn_mfma_f32_16x16x32_bf16(af[i], bf[j], acc[i][j], 0, 0, 0);
        __syncthreads();
    }

    const int seg = n0 >> 7;   // 0..5
    if (seg < 4) {
        unsigned short* dstbuf = ((seg < 2) ? qo : ko) + (size_t)(seg & 1) * QK_ELEMS;
        float freqj[4];
        #pragma unroll
        for (int j = 0; j < 4; ++j) {
            const int d = wc * 64 + j * 16 + l15;
            freqj[j] = __expf((float)(d >> 1) * (-LOG_THETA / 64.f));
        }
        const int odd = lane & 1;
        #pragma unroll
        for (int i = 0; i < 4; ++i) {
            #pragma unroll
            for (int e = 0; e < 4; ++e) {
                const int m = m0 + wr * 64 + i * 16 + quad * 4 + e;
                const float trow = (float)(m & (T_DIM - 1));
                unsigned int* p32 = (unsigned int*)(dstbuf + (size_t)m * HS_DIM);
                #pragma unroll
                for (int j = 0; j < 4; ++j) {
                    const int d = wc * 64 + j * 16 + l15;
                    const float val = acc[i][j][e];
                    const float other = __shfl_xor(val, 1);
                    float sn_, cs_;
                    __sincosf(trow * freqj[j], &sn_, &cs_);
                    const float out = val * cs_ + (odd ? other * sn_ : -other * sn_);
                    const float out2 = __shfl_xor(out, 1);
                    if (!odd) p32[d >> 1] = pack_bf2(out, out2);
                }
            }
        }
    } else {
        const int bq = m0 >> 11;
        const int tbase = m0 & (T_DIM - 1);
        unsigned int* vT32 = (unsigned int*)vo;
        #pragma unroll
        for (int j = 0; j < 4; ++j) {
            const int d = (seg - 4) * 128 + wc * 64 + j * 16 + l15;
            const size_t rowbase = (size_t)(bq * VD + d) * (T_DIM / 2); // u32 units
            #pragma unroll
            for (int i = 0; i < 4; ++i) {
                const int tok = tbase + wr * 64 + i * 16 + quad * 4;
                uint2 u;
                u.x = pack_bf2(acc[i][j][0], acc[i][j][1]);
                u.y = pack_bf2(acc[i][j][2], acc[i][j][3]);
                *(uint2*)&vT32[rowbase + (tok >> 1)] = u;
            }
        }
    }
}

// ---------- kernel 3: dual-term causal attention, 32x32 bf16 MFMA ----------
// Round-3 restructure (after R1: scattered reg loads = 3x L2 amplification;
// R2: reg-staged prefetch = 458 MB scratch spill):
//   - KVBLK=32, K/V DOUBLE-BUFFERED in LDS, staged via global_load_lds
//     (zero register cost, coalesced). Linear LDS rows + XOR-swizzle
//     (byte slot ^= row&7) with PRE-SWIZZLED global source (both-sides rule).
//   - Tile t+1's glds issued at top of tile t; the single end-of-tile
//     __syncthreads (compiler drains vmcnt) gives ~full-tile latency cover.
//   - Swapped QK (mfma(K,Q)): lane = query; P never touches LDS. PV A-frags
//     built in-register via packed shfl_xor(32) exchange (permlane dataflow).
//   - Waves = (term, dhalf): QK duplicated per d-half pair (MFMA util is low),
//     PV covers all 32 keys x 128 dims -> o[4] (64 AGPRs). ONE barrier/tile.
// LDS: 2 x (K 16 KB + V 16 KB) + Lsum 256 B = 65792 -> 2 blocks/CU.
#define KVB 32
#define BUFB 32768   // bytes per K+V buffer
#define LS_OFF 65536 // Lsum offset
#define SM_TOTAL 65792
#define OSTR 260     // O combine stride (fp32 words)

__global__ __launch_bounds__(256, 2) void attn_kernel(
    const unsigned short* __restrict__ qg, const unsigned short* __restrict__ kg,
    const unsigned short* __restrict__ vg, const float* __restrict__ lam,
    float* __restrict__ outp) {
    __shared__ __align__(16) unsigned char smem[SM_TOTAL];
    float* Lsum = (float*)(smem + LS_OFF);                 // [2 terms][32 q]
    float* Ol = (float*)smem;                              // [32][260] overlays bufs

    const int t = threadIdx.x;
    const int id = blockIdx.x;
    const int b = id & 7;                  // batch -> XCD round-robin
    const int sidx = id >> 3;              // 0..63
    const int strip = (sidx < 32) ? (63 - sidx) : (sidx - 32); // complementary pairing
    const int q0 = strip * 32;
    const int nt = strip + 1;              // 32-key tiles

    const int w = t >> 6, lane = t & 63;
    const int l31 = lane & 31, lh = lane >> 5;
    const int term = w & 1;
    const int dh = w >> 1;                 // PV d-half

    const float cn = lam[term];            // lam[1] carries the minus sign

    // Q B-frags (col=lane&31=query, k=lh*8+j): same addressing as before
    const unsigned short* qrow = qg
        + ((size_t)(term * B_DIM + b) * T_DIM + q0 + l31) * HS_DIM + lh * 8;
    s8v qa[8];
    #pragma unroll
    for (int ks = 0; ks < 8; ++ks)
        qa[ks] = *(const s8v*)(qrow + ks * 16);

    // ---- staging geometry: idx = t + rep*256 over 2048 glds-16B ----
    // K (idx 0..1023): term=idx>>9, row=(idx>>4)&31, slot=idx&15, swz=slot^(row&7)
    //   LDS linear dst = bufbase + idx*16 ; source pre-swizzled.
    // V (j=idx-1024): row=j>>3 (dim pair), slot=j&7, swz=slot^(row&7),
    //   dim=2*row+(swz>>2), tokchunk=swz&3 ; dst = bufbase+16384 + j*16.
    const unsigned short* ksrcb[4];
    const unsigned short* vsrcb[4];
    #pragma unroll
    for (int rep = 0; rep < 4; ++rep) {
        const int idx = t + rep * 256;
        const int kterm = idx >> 9, krow = (idx >> 4) & 31, kslot = idx & 15;
        const int ksw = kslot ^ (krow & 7);
        ksrcb[rep] = kg + ((size_t)(kterm * B_DIM + b) * T_DIM + krow) * HS_DIM + ksw * 8;
        const int j = idx;                 // V uses same 0..1023 range
        const int vrow = j >> 3, vslot = j & 7;
        const int vsw = vslot ^ (vrow & 7);
        const int vdim = 2 * vrow + (vsw >> 2), vtc = vsw & 3;
        vsrcb[rep] = vg + ((size_t)(b * VD + vdim)) * T_DIM + vtc * 8;
    }

    f32x16 o[4];
    #pragma unroll
    for (int dt = 0; dt < 4; ++dt)
        #pragma unroll
        for (int r = 0; r < 16; ++r) o[dt][r] = 0.f;
    float lsc = 0.f;

    // ---- prologue: stage tile 0 into buf 0 ----
    {
        unsigned short* kd = (unsigned short*)(smem) + t * 8;
        unsigned short* vd = (unsigned short*)(smem + 16384) + t * 8;
        #pragma unroll
        for (int rep = 0; rep < 4; ++rep) {
            async_cp16(ksrcb[rep], kd + rep * 2048);
            async_cp16(vsrcb[rep], vd + rep * 2048);
        }
    }
    __syncthreads();

    for (int it = 0; it < nt; ++it) {
        const int s0 = it * KVB;
        const int c = it & 1;
        unsigned char* buf = smem + c * BUFB;

        // ---- stage tile t+1 into the other buffer (async, zero regs) ----
        if (it + 1 < nt) {
            const int sn = s0 + KVB;
            unsigned char* nbuf = smem + (c ^ 1) * BUFB;
            unsigned short* kd = (unsigned short*)(nbuf) + t * 8;
            unsigned short* vd = (unsigned short*)(nbuf + 16384) + t * 8;
            #pragma unroll
            for (int rep = 0; rep < 4; ++rep) {
                async_cp16(ksrcb[rep] + (size_t)sn * HS_DIM, kd + rep * 2048);
                async_cp16(vsrcb[rep] + sn, vd + rep * 2048);
            }
        }

        // ---- QK swapped: S^T via mfma(K, Q): lane=query l31, regs=keys ----
        const unsigned short* Kb = (const unsigned short*)buf;
        f32x16 sc;
        #pragma unroll
        for (int r = 0; r < 16; ++r) sc[r] = 0.f;
        __builtin_amdgcn_s_setprio(1);
        #pragma unroll
        for (int ks = 0; ks < 8; ++ks) {
            const int slot = (ks * 2 + lh) ^ (l31 & 7);
            s8v kf = *(const s8v*)&Kb[((term * 32 + l31) * 16 + slot) * 8];
            sc = __builtin_amdgcn_mfma_f32_32x32x16_bf16(kf, qa[ks], sc, 0, 0, 0);
        }
        __builtin_amdgcn_s_setprio(0);

        // ---- exp + causal (key = s0+crow(r,lh), query = q0+l31) ----
        float p[16];
        #pragma unroll
        for (int r = 0; r < 16; ++r) {
            const int key = s0 + (r & 3) + 8 * (r >> 2) + 4 * lh;
            p[r] = (key <= q0 + l31) ? __expf(sc[r] * SCALE) : 0.f;
            lsc += p[r];
        }

        // ---- build PV A-frags in-register (permlane32_swap dataflow) ----
        // pa[ks] bf16 j = P[q=l31][key 16ks + 8lh + j]
        s8v pa[2];
        #pragma unroll
        for (int ks = 0; ks < 2; ++ks) {
            const unsigned int X0 = pack_bf2(p[8 * ks + 0], p[8 * ks + 1]);
            const unsigned int X1 = pack_bf2(p[8 * ks + 2], p[8 * ks + 3]);
            const unsigned int Y0 = pack_bf2(p[8 * ks + 4], p[8 * ks + 5]);
            const unsigned int Y1 = pack_bf2(p[8 * ks + 6], p[8 * ks + 7]);
            const unsigned int pX0 = __shfl_xor((int)X0, 32);
            const unsigned int pX1 = __shfl_xor((int)X1, 32);
            const unsigned int pY0 = __shfl_xor((int)Y0, 32);
            const unsigned int pY1 = __shfl_xor((int)Y1, 32);
            unsigned int wbuf[4];
            wbuf[0] = lh ? pY0 : X0;
            wbuf[1] = lh ? pY1 : X1;
            wbuf[2] = lh ? Y0 : pX0;
            wbuf[3] = lh ? Y1 : pX1;
            pa[ks] = *(const s8v*)wbuf;
        }

        // ---- PV: O[32q x 128d(dh)] += P[32x32] @ V[32x128] ----
        const unsigned short* Vb = (const unsigned short*)(buf + 16384);
        __builtin_amdgcn_s_setprio(1);
        #pragma unroll
        for (int ks = 0; ks < 2; ++ks) {
            #pragma unroll
            for (int dt = 0; dt < 4; ++dt) {
                const int dim = dh * 128 + dt * 32 + l31;
                const int vrow = dim >> 1;
                const int slot = ((dim & 1) * 4 + ks * 2 + lh) ^ (vrow & 7);
                s8v vb = *(const s8v*)&Vb[(vrow * 8 + slot) * 8];
                o[dt] = __builtin_amdgcn_mfma_f32_32x32x16_bf16(pa[ks], vb, o[dt], 0, 0, 0);
            }
        }
        __builtin_amdgcn_s_setprio(0);

        __syncthreads();   // drains glds (issued a full tile ago); flips buffer
    }

    // ---- softmax denominators: lane=query, combine lh halves in-wave ----
    const float ltot = lsc + __shfl_xor(lsc, 32);
    if (dh == 0 && lh == 0) Lsum[term * 32 + l31] = ltot;
    __syncthreads();
    float inv[16];
    #pragma unroll
    for (int r = 0; r < 16; ++r) {
        const int row = (r & 3) + 8 * (r >> 2) + 4 * lh;
        inv[r] = cn / Lsum[term * 32 + row];
    }

    // ---- combine terms via LDS overlay on buffers (Lsum region untouched) ----
    if (term) {
        #pragma unroll
        for (int dt = 0; dt < 4; ++dt)
            #pragma unroll
            for (int r = 0; r < 16; ++r) {
                const int row = (r & 3) + 8 * (r >> 2) + 4 * lh;
                Ol[row * OSTR + dh * 128 + dt * 32 + l31] = o[dt][r] * inv[r];
            }
    }
    __syncthreads();
    if (!term) {
        #pragma unroll
        for (int dt = 0; dt < 4; ++dt)
            #pragma unroll
            for (int r = 0; r < 16; ++r) {
                const int row = (r & 3) + 8 * (r >> 2) + 4 * lh;
                Ol[row * OSTR + dh * 128 + dt * 32 + l31] += o[dt][r] * inv[r];
            }
    }
    __syncthreads();
    #pragma unroll
    for (int rep = 0; rep < 8; ++rep) {
        int idx = t + rep * 256;           // 32 rows x 64 float4
        int row = idx >> 6, c4 = idx & 63;
        float4 val = *(const float4*)&Ol[row * OSTR + c4 * 4];
        *(float4*)&outp[((size_t)(b * T_DIM + q0 + row)) * VD + c4 * 4] = val;
    }
}

extern "C" void kernel_launch(void* const* d_in, const int* in_sizes, int n_in,
                              void* d_out, int out_size, void* d_ws, size_t ws_size,
                              hipStream_t stream) {
    const float* x  = (const float*)d_in[0];
    const float* Wq = (const float*)d_in[1];
    const float* Wk = (const float*)d_in[2];
    const float* Wv = (const float*)d_in[3];
    const float* lq = (const float*)d_in[4];
    const float* lk = (const float*)d_in[5];
    const int* lidx = (const int*)d_in[6];

    unsigned short* ws = (unsigned short*)d_ws;
    unsigned short* qb   = ws + QB_OFF;    // [2][8][2048][128] bf16
    unsigned short* kb   = ws + KB_OFF;    // [2][8][2048][128] bf16
    unsigned short* vTb  = ws + VT_OFF;    // [8][256][2048] bf16
    unsigned short* wtb  = ws + WT_OFF;    // [768][1024] bf16
    unsigned short* xbhi = ws + XBH_OFF;   // x-bf16 rows 8192..16383
    float* lamb = (float*)(ws + LAM_OFF);
    unsigned short* xblo = (unsigned short*)d_out;  // scratch; attn overwrites d_out
    (void)ws_size; (void)in_sizes; (void)n_in; (void)out_size;

    lam_kernel<<<dim3(1), dim3(64), 0, stream>>>(lq, lk, lidx, lamb);
    cast_x_kernel<<<dim3(8192), dim3(256), 0, stream>>>(x, xblo, xbhi);
    cast_wt_kernel<<<dim3(24, 32), dim3(256), 0, stream>>>(Wq, Wk, Wv, wtb);
    gemm_kernel<<<dim3(128, 6), dim3(256), 0, stream>>>(xblo, xbhi, wtb, qb, kb, vTb);
    attn_kernel<<<dim3(512), dim3(256), 0, stream>>>(qb, kb, vTb, lamb, (float*)d_out);
}

// Round 4
// 232.575 us; speedup vs baseline: 1.8167x; 1.0977x over previous
//
#include <hip/hip_runtime.h>
#include <math.h>

// Problem constants
#define B_DIM 8
#define T_DIM 2048
#define C_DIM 1024
#define HS_DIM 128
#define VD 256
#define M_DIM (B_DIM * T_DIM)            // 16384 rows
#define QK_ELEMS (M_DIM * HS_DIM)        // 2,097,152 elems per (q|k) term
#define SCALE 0.088388347648318447f      // 1/sqrt(128)
#define LOG_THETA 9.210340371976184f     // ln(10000)

// workspace layout (ushort units)
#define QB_OFF   0u
#define KB_OFF   4194304u
#define VT_OFF   8388608u
#define WT_OFF   12582912u
#define XBH_OFF  13369344u               // x-bf16 rows 8192..16383
#define LAM_OFF  21757952u
#define XSPLIT_ELEMS 8388608u            // rows 0..8191 of x-bf16 live in d_out

typedef short s8v   __attribute__((ext_vector_type(8)));   // 8 bf16 (4 VGPRs)
typedef float f32x4 __attribute__((ext_vector_type(4)));
typedef float f32x16 __attribute__((ext_vector_type(16)));

// ---------- helpers ----------
__device__ __forceinline__ unsigned int bf16_rne(float f) {
    unsigned int u = __float_as_uint(f);
    return (u + 0x7fffu + ((u >> 16) & 1u)) >> 16;
}
__device__ __forceinline__ unsigned int pack_bf2(float lo, float hi) {
    return bf16_rne(lo) | (bf16_rne(hi) << 16);
}
__device__ __forceinline__ void async_cp16(const unsigned short* g, unsigned short* l) {
    __builtin_amdgcn_global_load_lds(
        (const __attribute__((address_space(1))) unsigned int*)g,
        (__attribute__((address_space(3))) unsigned int*)l, 16, 0, 0);
}

// ---------- kernel 1: lambda coefficients ----------
__global__ void lam_kernel(const float* __restrict__ lq, const float* __restrict__ lk,
                           const int* __restrict__ lidx, float* __restrict__ lam_out) {
    int t = threadIdx.x; // 64 threads = 1 wave
    float s0 = expf(lq[t] * lk[t]) + expf(lq[t + 64] * lk[t + 64]);
    float s1 = expf(lq[128 + t] * lk[128 + t]) + expf(lq[192 + t] * lk[192 + t]);
    #pragma unroll
    for (int off = 32; off > 0; off >>= 1) {
        s0 += __shfl_down(s0, off);
        s1 += __shfl_down(s1, off);
    }
    if (t == 0) {
        float e0 = s0 * (1.0f / 128.0f);
        float e1 = s1 * (1.0f / 128.0f);
        float li = 0.8f - 0.6f * expf(-0.3f * ((float)lidx[0] - 1.0f));
        lam_out[0] = e0 + li;            // +lam0
        lam_out[1] = -(e1 - e0 + li);    // -lam1
    }
}

// ---------- kernel 2a: cast x -> bf16 (split across d_out scratch + ws) ----------
__global__ __launch_bounds__(256) void cast_x_kernel(const float* __restrict__ x,
                                                     unsigned short* __restrict__ lo,
                                                     unsigned short* __restrict__ hi) {
    const size_t i8 = ((size_t)blockIdx.x * 256 + threadIdx.x) * 8;
    float4 a = *(const float4*)(x + i8);
    float4 b = *(const float4*)(x + i8 + 4);
    uint4 u;
    u.x = pack_bf2(a.x, a.y); u.y = pack_bf2(a.z, a.w);
    u.z = pack_bf2(b.x, b.y); u.w = pack_bf2(b.z, b.w);
    unsigned short* dst = (i8 < XSPLIT_ELEMS) ? (lo + i8) : (hi + (i8 - XSPLIT_ELEMS));
    *(uint4*)dst = u;
}

// ---------- kernel 2b: build Wt[768][1024] bf16 (transposed, concatenated) ----
__global__ __launch_bounds__(256) void cast_wt_kernel(
    const float* __restrict__ Wq, const float* __restrict__ Wk,
    const float* __restrict__ Wv, unsigned short* __restrict__ wt) {
    __shared__ float tile[32][33];
    const int t = threadIdx.x;
    const int n0 = blockIdx.x * 32;
    const int k0 = blockIdx.y * 32;
    const int seg = n0 >> 7;
    const int nl = t & 31;
    const int ng = n0 + nl;
    const float* src; int ld;
    if (seg < 2)      { src = Wq + (size_t)seg * (C_DIM * HS_DIM) + (ng & 127); ld = 128; }
    else if (seg < 4) { src = Wk + (size_t)(seg - 2) * (C_DIM * HS_DIM) + (ng & 127); ld = 128; }
    else              { src = Wv + (ng - 512); ld = 256; }
    #pragma unroll
    for (int rep = 0; rep < 4; ++rep) {
        int kl = (t >> 5) + rep * 8;
        tile[kl][nl] = src[(size_t)(k0 + kl) * ld];
    }
    __syncthreads();
    unsigned int* wt32 = (unsigned int*)wt;
    #pragma unroll
    for (int rep = 0; rep < 2; ++rep) {
        int nl2 = (t >> 4) + rep * 16;
        int k2 = (t & 15) * 2;
        unsigned int u = pack_bf2(tile[k2][nl2], tile[k2 + 1][nl2]);
        wt32[((size_t)(n0 + nl2) * 1024 + k0 + k2) >> 1] = u;
    }
}

// ---------- kernel 2c: bf16 MFMA GEMM + RoPE / V-transpose epilogue ----------
__global__ __launch_bounds__(256) void gemm_kernel(
    const unsigned short* __restrict__ xlo, const unsigned short* __restrict__ xhi,
    const unsigned short* __restrict__ wt,
    unsigned short* __restrict__ qo, unsigned short* __restrict__ ko,
    unsigned short* __restrict__ vo) {
    __shared__ unsigned short As[128 * 32];   // 8 KB, row-major [128][32]
    __shared__ unsigned short Bs[128 * 32];   // 8 KB, row-major [128][32]

    const int t = threadIdx.x;
    const int wv = t >> 6, lane = t & 63;
    const int quad = lane >> 4, l15 = lane & 15;
    const int m0 = blockIdx.x * 128;
    const int n0 = blockIdx.y * 128;
    const int wr = wv >> 1, wc = wv & 1;

    const unsigned short* xbase = (m0 < 8192)
        ? (xlo + (size_t)m0 * C_DIM) : (xhi + (size_t)(m0 - 8192) * C_DIM);

    f32x4 acc[4][4];
    #pragma unroll
    for (int i = 0; i < 4; ++i)
        #pragma unroll
        for (int j = 0; j < 4; ++j) acc[i][j] = (f32x4){0.f, 0.f, 0.f, 0.f};

    const int srow = lane >> 2;
    const int skof = (lane & 3) * 8;

    for (int k0 = 0; k0 < C_DIM; k0 += 32) {
        #pragma unroll
        for (int j = 0; j < 2; ++j) {
            const int c = wv * 2 + j;
            async_cp16(xbase + (size_t)(c * 16 + srow) * C_DIM + k0 + skof, As + c * 512);
        }
        #pragma unroll
        for (int j = 0; j < 2; ++j) {
            const int c = wv * 2 + j;
            async_cp16(wt + (size_t)(n0 + c * 16 + srow) * C_DIM + k0 + skof, Bs + c * 512);
        }
        __syncthreads();
        s8v af[4], bf[4];
        #pragma unroll
        for (int i = 0; i < 4; ++i)
            af[i] = *(const s8v*)&As[(wr * 64 + i * 16 + l15) * 32 + quad * 8];
        #pragma unroll
        for (int j = 0; j < 4; ++j)
            bf[j] = *(const s8v*)&Bs[(wc * 64 + j * 16 + l15) * 32 + quad * 8];
        #pragma unroll
        for (int i = 0; i < 4; ++i)
            #pragma unroll
            for (int j = 0; j < 4; ++j)
                acc[i][j] = __builtin_amdgcn_mfma_f32_16x16x32_bf16(af[i], bf[j], acc[i][j], 0, 0, 0);
        __syncthreads();
    }

    const int seg = n0 >> 7;   // 0..5
    if (seg < 4) {
        unsigned short* dstbuf = ((seg < 2) ? qo : ko) + (size_t)(seg & 1) * QK_ELEMS;
        float freqj[4];
        #pragma unroll
        for (int j = 0; j < 4; ++j) {
            const int d = wc * 64 + j * 16 + l15;
            freqj[j] = __expf((float)(d >> 1) * (-LOG_THETA / 64.f));
        }
        const int odd = lane & 1;
        #pragma unroll
        for (int i = 0; i < 4; ++i) {
            #pragma unroll
            for (int e = 0; e < 4; ++e) {
                const int m = m0 + wr * 64 + i * 16 + quad * 4 + e;
                const float trow = (float)(m & (T_DIM - 1));
                unsigned int* p32 = (unsigned int*)(dstbuf + (size_t)m * HS_DIM);
                #pragma unroll
                for (int j = 0; j < 4; ++j) {
                    const int d = wc * 64 + j * 16 + l15;
                    const float val = acc[i][j][e];
                    const float other = __shfl_xor(val, 1);
                    float sn_, cs_;
                    __sincosf(trow * freqj[j], &sn_, &cs_);
                    const float out = val * cs_ + (odd ? other * sn_ : -other * sn_);
                    const float out2 = __shfl_xor(out, 1);
                    if (!odd) p32[d >> 1] = pack_bf2(out, out2);
                }
            }
        }
    } else {
        const int bq = m0 >> 11;
        const int tbase = m0 & (T_DIM - 1);
        unsigned int* vT32 = (unsigned int*)vo;
        #pragma unroll
        for (int j = 0; j < 4; ++j) {
            const int d = (seg - 4) * 128 + wc * 64 + j * 16 + l15;
            const size_t rowbase = (size_t)(bq * VD + d) * (T_DIM / 2); // u32 units
            #pragma unroll
            for (int i = 0; i < 4; ++i) {
                const int tok = tbase + wr * 64 + i * 16 + quad * 4;
                uint2 u;
                u.x = pack_bf2(acc[i][j][0], acc[i][j][1]);
                u.y = pack_bf2(acc[i][j][2], acc[i][j][3]);
                *(uint2*)&vT32[rowbase + (tok >> 1)] = u;
            }
        }
    }
}

// ---------- kernel 3: dual-term causal attention, 32x32 bf16 MFMA ----------
// Grid: 512 blocks = 64 strips x 8 batches; strip order pairs complementary
// heavy/light strips; blocks id and id+256 co-reside on one CU (2 blocks/CU).
// Block: 256 threads / 4 waves; strip = 32 queries; K-tile = 64 keys.
//
// Round-4: round-0 structure VERBATIM except V LDS geometry. Round 0 ran at
// 1 block/CU because LDS=80896 B is 896 B over the 80 KB two-block threshold
// (Occupancy 13% = 1 wave/SIMD -> all staging latency exposed, 5530 cyc/tile
// vs ~600 throughput cycles). Fix: V tile unpadded (stride 72 -> 64 ushorts)
// with 16B-slot XOR swizzle (slot ^= row&7) applied on BOTH the reg-staged
// write and the PV read. 8-lane-phase bank analysis: each 8 lanes hit 8
// distinct 4-bank groups -> conflict-free (same class as the measured-0 K
// pattern; round-3's 4.26M conflicts were the shfl_xor ds_permutes, absent
// here). LDS: 34816(K)+32768(V)+9216(P) = 76800 B -> 2 blocks/CU.
#define KSTR 136    // K LDS row stride (bf16)
#define PSTR 72     // P LDS row stride: 64 keys + 8 pad
#define OSTR 260    // O combine stride (fp32 words)
#define K_OFF 0
#define V_OFF 34816
#define P_OFF 67584
#define SM_TOTAL 76800

__global__ __launch_bounds__(256, 2) void attn_kernel(
    const unsigned short* __restrict__ qg, const unsigned short* __restrict__ kg,
    const unsigned short* __restrict__ vg, const float* __restrict__ lam,
    float* __restrict__ outp) {
    __shared__ __align__(16) unsigned char smem[SM_TOTAL];
    unsigned short* Ks = (unsigned short*)(smem + K_OFF);  // [2][64][136]
    unsigned short* Vt = (unsigned short*)(smem + V_OFF);  // [256][64] swizzled
    unsigned short* Ps = (unsigned short*)(smem + P_OFF);  // [2][32][72]
    float* Ol = (float*)smem;                              // [32][260] overlays K
    float* Lsum = (float*)(smem + P_OFF);                  // [2][2][32] overlays dead Ps

    const int t = threadIdx.x;
    const int id = blockIdx.x;
    const int b = id & 7;                  // batch -> XCD round-robin
    const int sidx = id >> 3;              // 0..63
    const int strip = (sidx < 32) ? (63 - sidx) : (sidx - 32); // complementary pairing
    const int q0 = strip * 32;
    const int nt = (strip >> 1) + 1;       // 64-key tiles

    const int w = t >> 6, lane = t & 63;
    const int l31 = lane & 31, lh = lane >> 5;
    const int term = w & 1;
    const int kh = w >> 1;                 // QK k-half / PV d-half

    const float cn = lam[term];            // lam[1] carries the minus sign

    // Q A-frags (32x32x16 layout: row=lane&31, k=lh*8+j), 8 k-steps in registers
    const unsigned short* qrow = qg
        + ((size_t)(term * B_DIM + b) * T_DIM + q0 + l31) * HS_DIM + lh * 8;
    s8v qa[8];
    #pragma unroll
    for (int ks = 0; ks < 8; ++ks)
        qa[ks] = *(const s8v*)(qrow + ks * 16);

    f32x16 o[4];
    #pragma unroll
    for (int dt = 0; dt < 4; ++dt)
        #pragma unroll
        for (int r = 0; r < 16; ++r) o[dt][r] = 0.f;
    float l_acc[16];
    #pragma unroll
    for (int r = 0; r < 16; ++r) l_acc[r] = 0.f;

    for (int it = 0; it < nt; ++it) {
        const int s0 = it * 64;
        // ---- stage K (2 terms x 64 keys x 128) ----
        #pragma unroll
        for (int rep = 0; rep < 8; ++rep) {
            int idx = t + rep * 256;       // 0..2047 uint4s
            int n = idx >> 10, rem = idx & 1023;
            int r = rem >> 4, seg = rem & 15;
            const uint4 g = *(const uint4*)(kg
                + ((size_t)(n * B_DIM + b) * T_DIM + s0 + r) * HS_DIM + seg * 8);
            *(uint4*)&Ks[(n * 64 + r) * KSTR + seg * 8] = g;
        }
        // ---- stage Vt (256 dims x 64 tokens), 16B-slot XOR swizzle ----
        #pragma unroll
        for (int rep = 0; rep < 8; ++rep) {
            int idx = t + rep * 256;       // 0..2047 uint4s
            int d = idx >> 3, seg = idx & 7;
            const uint4 g = *(const uint4*)(vg
                + ((size_t)(b * VD + d) * T_DIM + s0) + seg * 8);
            *(uint4*)&Vt[d * 64 + ((seg ^ (d & 7)) * 8)] = g;
        }
        __syncthreads();

        // ---- QK: S[32q x 32k] for (term, khalf) ----
        f32x16 sc;
        #pragma unroll
        for (int r = 0; r < 16; ++r) sc[r] = 0.f;
        #pragma unroll
        for (int ks = 0; ks < 8; ++ks) {
            s8v kf = *(const s8v*)&Ks[(term * 64 + kh * 32 + l31) * KSTR
                                      + ks * 16 + lh * 8];
            sc = __builtin_amdgcn_mfma_f32_32x32x16_bf16(qa[ks], kf, sc, 0, 0, 0);
        }
        // exp + P write (C/D 32x32: col=l31, row=(r&3)+8*(r>>2)+4*lh)
        const int key = s0 + kh * 32 + l31;
        #pragma unroll
        for (int r = 0; r < 16; ++r) {
            const int row = (r & 3) + 8 * (r >> 2) + 4 * lh;
            const float p = (key <= q0 + row) ? __expf(sc[r] * SCALE) : 0.f;
            l_acc[r] += p;
            Ps[(term * 32 + row) * PSTR + kh * 32 + l31] = (unsigned short)bf16_rne(p);
        }
        __syncthreads();

        // ---- PV: O[32q x 128d] += P[32x64] @ V[64x128] for (term, dhalf) ----
        #pragma unroll
        for (int ks = 0; ks < 4; ++ks) {
            s8v pa = *(const s8v*)&Ps[(term * 32 + l31) * PSTR + ks * 16 + lh * 8];
            #pragma unroll
            for (int dt = 0; dt < 4; ++dt) {
                const int vrow = kh * 128 + dt * 32 + l31;
                s8v vb = *(const s8v*)&Vt[vrow * 64
                                          + (((ks * 2 + lh) ^ (l31 & 7)) * 8)];
                o[dt] = __builtin_amdgcn_mfma_f32_32x32x16_bf16(pa, vb, o[dt], 0, 0, 0);
            }
        }
        __syncthreads();
    }

    // ---- finalize l: intra-wave reduce over 32 key-columns, then combine
    //      the two kh-wave partials per (term,row) through LDS ----
    #pragma unroll
    for (int r = 0; r < 16; ++r) {
        float lt = l_acc[r];
        #pragma unroll
        for (int off = 1; off < 32; off <<= 1) lt += __shfl_xor(lt, off);
        if (l31 == 0) {
            const int row = (r & 3) + 8 * (r >> 2) + 4 * lh;
            Lsum[(term * 2 + kh) * 32 + row] = lt;
        }
    }
    __syncthreads();
    float inv[16];
    #pragma unroll
    for (int r = 0; r < 16; ++r) {
        const int row = (r & 3) + 8 * (r >> 2) + 4 * lh;
        inv[r] = cn / (Lsum[(term * 2 + 0) * 32 + row] + Lsum[(term * 2 + 1) * 32 + row]);
    }

    // ---- combine terms via LDS overlay on K region ----
    if (term) {
        #pragma unroll
        for (int dt = 0; dt < 4; ++dt)
            #pragma unroll
            for (int r = 0; r < 16; ++r) {
                const int row = (r & 3) + 8 * (r >> 2) + 4 * lh;
                Ol[row * OSTR + kh * 128 + dt * 32 + l31] = o[dt][r] * inv[r];
            }
    }
    __syncthreads();
    if (!term) {
        #pragma unroll
        for (int dt = 0; dt < 4; ++dt)
            #pragma unroll
            for (int r = 0; r < 16; ++r) {
                const int row = (r & 3) + 8 * (r >> 2) + 4 * lh;
                Ol[row * OSTR + kh * 128 + dt * 32 + l31] += o[dt][r] * inv[r];
            }
    }
    __syncthreads();
    #pragma unroll
    for (int rep = 0; rep < 8; ++rep) {
        int idx = t + rep * 256;           // 32 rows x 64 float4
        int row = idx >> 6, c4 = idx & 63;
        float4 val = *(const float4*)&Ol[row * OSTR + c4 * 4];
        *(float4*)&outp[((size_t)(b * T_DIM + q0 + row)) * VD + c4 * 4] = val;
    }
}

extern "C" void kernel_launch(void* const* d_in, const int* in_sizes, int n_in,
                              void* d_out, int out_size, void* d_ws, size_t ws_size,
                              hipStream_t stream) {
    const float* x  = (const float*)d_in[0];
    const float* Wq = (const float*)d_in[1];
    const float* Wk = (const float*)d_in[2];
    const float* Wv = (const float*)d_in[3];
    const float* lq = (const float*)d_in[4];
    const float* lk = (const float*)d_in[5];
    const int* lidx = (const int*)d_in[6];

    unsigned short* ws = (unsigned short*)d_ws;
    unsigned short* qb   = ws + QB_OFF;    // [2][8][2048][128] bf16
    unsigned short* kb   = ws + KB_OFF;    // [2][8][2048][128] bf16
    unsigned short* vTb  = ws + VT_OFF;    // [8][256][2048] bf16
    unsigned short* wtb  = ws + WT_OFF;    // [768][1024] bf16
    unsigned short* xbhi = ws + XBH_OFF;   // x-bf16 rows 8192..16383
    float* lamb = (float*)(ws + LAM_OFF);
    unsigned short* xblo = (unsigned short*)d_out;  // scratch; attn overwrites d_out
    (void)ws_size; (void)in_sizes; (void)n_in; (void)out_size;

    lam_kernel<<<dim3(1), dim3(64), 0, stream>>>(lq, lk, lidx, lamb);
    cast_x_kernel<<<dim3(8192), dim3(256), 0, stream>>>(x, xblo, xbhi);
    cast_wt_kernel<<<dim3(24, 32), dim3(256), 0, stream>>>(Wq, Wk, Wv, wtb);
    gemm_kernel<<<dim3(128, 6), dim3(256), 0, stream>>>(xblo, xbhi, wtb, qb, kb, vTb);
    attn_kernel<<<dim3(512), dim3(256), 0, stream>>>(qb, kb, vTb, lamb, (float*)d_out);
}